// Round 8
// baseline (414.370 us; speedup 1.0000x reference)
//
#include <hip/hip_runtime.h>

// CRF forward partition, MI355X. B=1024, L=512, T=52 (padded to 64).
//
// R8: R7's MFMA structure (verified correct) with the serial chain stripped:
//  - exp(feats) precomputed into a 2-step ring at group boundaries (off-chain)
//  - independent partial MFMAs with a reusable zero-C (no dependent pair, no
//    per-step acc zero-init)
//  - bf16 pack via add+v_perm (3 insts / 2 values)
//  - renorm every 4 steps, log2-units bookkeeping (native v_log_f32)
//  - ring kept small (~160 live VGPRs) to avoid R7's AGPR parking of the
//    128-reg double buffer.
// Layouts (verified by R7 passing): D/C row=quad*4+reg col=lane&15;
// A[m=lane&15][k=quad*8+jj]; B[k=quad*8+jj][n=lane&15].

#define TT 52
#define LL 512
#define BT 16   // batches per wave

typedef __attribute__((ext_vector_type(8))) short s16x8;
typedef __attribute__((ext_vector_type(4))) float f32x4;

__device__ __forceinline__ float bperm_f(int srclane, float v) {
    return __int_as_float(__builtin_amdgcn_ds_bpermute(srclane * 4, __float_as_int(v)));
}
__device__ __forceinline__ short f2bf(float f) {   // RNE f32 -> bf16 bits
    unsigned u = __float_as_uint(f);
    u = (u + 0x7FFFu + ((u >> 16) & 1u)) >> 16;
    return (short)u;
}
// pack two f32 -> two bf16 (round-half-up) in one dword: low=a, high=b
__device__ __forceinline__ unsigned pk2(float a, float b) {
    unsigned ua = __float_as_uint(a) + 0x8000u;
    unsigned ub = __float_as_uint(b) + 0x8000u;
    return __builtin_amdgcn_perm(ub, ua, 0x07060302);
}

__global__ void __launch_bounds__(64)
__attribute__((amdgpu_waves_per_eu(1, 1)))
crf_fwd(const float* __restrict__ feats, const int* __restrict__ mask,
        const float* __restrict__ trans, float* __restrict__ out)
{
    __shared__ __align__(16) short lq[8 * 128];   // bf16 Q in B-frag order

    const int lane = threadIdx.x;
    const int c = lane & 15;          // batch col
    const int q = lane >> 4;          // quad
    const int b0 = blockIdx.x * BT;

    const float* fb = feats + (size_t)(b0 + c) * LL * TT;
    const int*   mb = mask  + (size_t)(b0 + c) * LL;

    int tb[4];
#pragma unroll
    for (int tt = 0; tt < 4; ++tt)
        tb[tt] = tt * 16 + ((tt == 3 && q > 0) ? 0 : q * 4);

    int woff[4];
#pragma unroll
    for (int tt = 0; tt < 4; ++tt) {
        int X = (tt >> 1) * 4 + ((2 * tt + (q >> 1)) & 3);
        woff[tt] = X * 128 + c * 8 + (q & 1) * 4;
    }
    const int roff0 = q * 128 + c * 8;
    const int roff1 = (4 + q) * 128 + c * 8;

    // A fragments (constant): exp(trans), zero outside 52x52
    s16x8 A[4][2];
#pragma unroll
    for (int jt = 0; jt < 4; ++jt)
#pragma unroll
        for (int kb = 0; kb < 2; ++kb)
#pragma unroll
            for (int jj = 0; jj < 8; ++jj) {
                int i = kb * 32 + q * 8 + jj;
                int j = jt * 16 + c;
                int ii = i < TT ? i : TT - 1;
                int jc2 = j < TT ? j : TT - 1;
                float e = __expf(trans[ii * TT + jc2]);
                A[jt][kb][jj] = (i < TT && j < TT) ? f2bf(e) : (short)0;
            }

    f32x4 eend[4];
#pragma unroll
    for (int tt = 0; tt < 4; ++tt)
#pragma unroll
        for (int r = 0; r < 4; ++r) {
            int g = tt * 16 + q * 4 + r;
            int gc = g < TT ? g : TT - 1;
            float e = __expf(trans[gc * TT + (TT - 1)]);
            eend[tt][r] = (g < TT) ? e : 0.0f;
        }

    // init t=0
    float shift2;                      // log2-units accumulated shift
    f32x4 pv[4];
    {
        f32x4 f0[4], ts[4];
#pragma unroll
        for (int tt = 0; tt < 4; ++tt) {
            f0[tt] = *(const f32x4*)(fb + tb[tt]);
            ts[tt] = *(const f32x4*)(trans + (TT - 2) * TT + tb[tt]);
        }
        float p00 = f0[0][0] + ts[0][0];
        float sh = bperm_f(c, p00);    // ln-units init shift
        shift2 = sh * 1.4426950408889634f;
#pragma unroll
        for (int tt = 0; tt < 4; ++tt) {
            float pm = (tt == 3 && q > 0) ? 0.0f : 1.0f;
#pragma unroll
            for (int r = 0; r < 4; ++r)
                pv[tt][r] = pm * __expf(f0[tt][r] + ts[tt][r] - sh);
        }
    }

    const f32x4 Z = {0.0f, 0.0f, 0.0f, 0.0f};

    // 2-step rings: EFF holds exp(feats) for the current group; FRW raw loads
    // for the next group.
    f32x4 EFF[2][4], FRW[2][4];
    int   MS[2], MR[2];
#pragma unroll
    for (int u = 0; u < 2; ++u) {
        int t = 1 + u;
#pragma unroll
        for (int tt = 0; tt < 4; ++tt)
            FRW[u][tt] = *(const f32x4*)(fb + (size_t)t * TT + tb[tt]);
        MR[u] = mb[t];
    }
#pragma unroll
    for (int u = 0; u < 2; ++u) {
#pragma unroll
        for (int tt = 0; tt < 4; ++tt)
#pragma unroll
            for (int r = 0; r < 4; ++r)
                EFF[u][tt][r] = __expf(FRW[u][tt][r]);
        MS[u] = MR[u];
    }
#pragma unroll
    for (int u = 0; u < 2; ++u) {
        int t = 3 + u;
#pragma unroll
        for (int tt = 0; tt < 4; ++tt)
            FRW[u][tt] = *(const f32x4*)(fb + (size_t)t * TT + tb[tt]);
        MR[u] = mb[t];
    }

#define STEP(EFv, Mv)                                                        \
    do {                                                                     \
        unsigned w0, w1;                                                     \
        _Pragma("unroll")                                                    \
        for (int tt = 0; tt < 4; ++tt) {                                     \
            w0 = pk2(pv[tt][0], pv[tt][1]);                                  \
            w1 = pk2(pv[tt][2], pv[tt][3]);                                  \
            ((unsigned*)&lq[woff[tt]])[0] = w0;                              \
            ((unsigned*)&lq[woff[tt]])[1] = w1;                              \
        }                                                                    \
        s16x8 B0 = *(s16x8*)&lq[roff0];                                      \
        s16x8 B1 = *(s16x8*)&lq[roff1];                                      \
        bool mm = (Mv) > 0;                                                  \
        _Pragma("unroll")                                                    \
        for (int tt = 0; tt < 4; ++tt) {                                     \
            f32x4 Da = __builtin_amdgcn_mfma_f32_16x16x32_bf16(A[tt][0], B0, Z, 0, 0, 0); \
            f32x4 Db = __builtin_amdgcn_mfma_f32_16x16x32_bf16(A[tt][1], B1, Z, 0, 0, 0); \
            f32x4 pn = (Da + Db) * (EFv)[tt];                                \
            _Pragma("unroll")                                                \
            for (int r = 0; r < 4; ++r)                                      \
                pv[tt][r] = mm ? pn[r] : pv[tt][r];                          \
        }                                                                    \
    } while (0)

    // main loop: groups of 2 steps, t = 1..510; renorm every 4 steps
    for (int t0 = 1; t0 <= LL - 3; t0 += 2) {
        STEP(EFF[0], MS[0]);
        STEP(EFF[1], MS[1]);
        if (((t0 >> 1) & 1) == 1) {          // t0 = 3,7,11,... every 4 steps
            float c0 = bperm_f(c, pv[0][0]); // tag0 of batch c (always > 0)
            shift2 += __log2f(c0);
            float ic = __builtin_amdgcn_rcpf(c0);
#pragma unroll
            for (int tt = 0; tt < 4; ++tt) pv[tt] *= ic;
        }
        // next group's exps (loads issued one group ago have landed)
#pragma unroll
        for (int u = 0; u < 2; ++u) {
#pragma unroll
            for (int tt = 0; tt < 4; ++tt)
#pragma unroll
                for (int r = 0; r < 4; ++r)
                    EFF[u][tt][r] = __expf(FRW[u][tt][r]);
            MS[u] = MR[u];
        }
        // issue loads two groups ahead
#pragma unroll
        for (int u = 0; u < 2; ++u) {
            int tn = t0 + 4 + u;
            tn = tn < LL ? tn : LL - 1;
#pragma unroll
            for (int tt = 0; tt < 4; ++tt)
                FRW[u][tt] = *(const f32x4*)(fb + (size_t)tn * TT + tb[tt]);
            MR[u] = mb[tn];
        }
    }
    // final step t = 511
    STEP(EFF[0], MS[0]);
#undef STEP

    // epilogue: res_b = (log2(sum_tag eend*pv) + shift2)*ln2; out += sum_b
    float val = 0.0f;
#pragma unroll
    for (int tt = 0; tt < 4; ++tt)
#pragma unroll
        for (int r = 0; r < 4; ++r)
            val = fmaf(eend[tt][r], pv[tt][r], val);
    val += __shfl_xor(val, 16);
    val += __shfl_xor(val, 32);
    float res = (__log2f(val) + shift2) * 0.6931471805599453f;
    float contrib = (q == 0) ? res : 0.0f;
#pragma unroll
    for (int o = 1; o <= 32; o <<= 1)
        contrib += __shfl_xor(contrib, o);
    if (lane == 0) atomicAdd(out, contrib);
}

extern "C" void kernel_launch(void* const* d_in, const int* in_sizes, int n_in,
                              void* d_out, int out_size, void* d_ws, size_t ws_size,
                              hipStream_t stream) {
    const float* feats = (const float*)d_in[0];
    const int*   mask  = (const int*)d_in[1];
    const float* trans = (const float*)d_in[2];
    float* out = (float*)d_out;

    const int B = in_sizes[1] / LL;   // mask is (B, L)

    hipMemsetAsync(d_out, 0, sizeof(float), stream);
    crf_fwd<<<B / BT, 64, 0, stream>>>(feats, mask, trans, out);
}